// Round 1
// baseline (231.593 us; speedup 1.0000x reference)
//
#include <hip/hip_runtime.h>
#include <stdint.h>

#define NIMG 32
#define CH 32
#define HH 160
#define WW 160
#define HWL (HH*WW)            // 25600
#define PRS 164                // padded row stride (words), 16B-aligned rows
#define PHH 162
#define PIMG (PHH*PRS)         // 26568 words per image (padded)
#define NPIX (NIMG*HWL)        // 819200 pixels

// workspace layout (bytes)
#define OFF_P    0
#define OFF_Y    3400704                   // P: 32*26568*4 = 3,400,704
#define OFF_WP   (OFF_Y + 52428800)        // Y: 26,214,400 int16
#define OFF_CORR (OFF_WP + 2304)           // 2 convs * 288 u32
#define OFF_SC   (OFF_CORR + 2304)         // 2 convs * 288 int
#define OFF_S1   (OFF_SC + 16)             // 2 floats (padded)
#define OFF_S2   (OFF_S1 + 256)            // 2*32 int
#define OFF_AB   (OFF_S2 + 512)            // 2*32 u64 ; then A1,B1,A2,B2 (128 floats)

// ---------------- prep: weight scales, bit-pack, border corrections, zero stats
__global__ __launch_bounds__(256) void prep_k(const float* __restrict__ w1,
    const float* __restrict__ w2, uint32_t* __restrict__ WP, int* __restrict__ CORR,
    float* __restrict__ SC, int* __restrict__ S1, unsigned long long* __restrict__ S2)
{
  __shared__ float red[256];
  const int tid = threadIdx.x;
  if (tid < 32) { S1[tid] = 0; S1[32 + tid] = 0; S2[tid] = 0; S2[32 + tid] = 0; }

  for (int cv = 0; cv < 2; ++cv) {
    const float* w = cv ? w2 : w1;
    float s = 0.f;
    for (int i = tid; i < 9216; i += 256) s += fabsf(w[i]);
    red[tid] = s;
    __syncthreads();
    for (int st = 128; st > 0; st >>= 1) {
      if (tid < st) red[tid] += red[tid + st];
      __syncthreads();
    }
    if (tid == 0) SC[cv] = red[0] / 9216.0f;

    // pack: WP[cv*288 + co*9 + t], bit ci = (w[co][ci][t] > 0)
    for (int i = tid; i < 288; i += 256) {
      int co = i / 9, t = i - co * 9;
      uint32_t b = 0;
      for (int ci = 0; ci < 32; ++ci) {
        float v = w[(co * 32 + ci) * 9 + t];
        b |= (v > 0.0f) ? (1u << ci) : 0u;
      }
      WP[cv * 288 + i] = b;
    }
    __syncthreads();
    // border-class corrections: CORR[cv*288 + cls*32 + co]
    for (int i = tid; i < 288; i += 256) {
      int cls = i / 32, co = i - cls * 32;
      int hc = cls / 3, wc = cls - hc * 3;
      int corr = 0;
      for (int t = 0; t < 9; ++t) {
        int dy = t / 3 - 1, dx = t % 3 - 1;
        bool inval = (hc == 0 && dy == -1) || (hc == 2 && dy == 1) ||
                     (wc == 0 && dx == -1) || (wc == 2 && dx == 1);
        if (inval) corr += 32 - 2 * __popc(WP[cv * 288 + co * 9 + t]);
      }
      CORR[cv * 288 + cls * 32 + co] = corr;
    }
    __syncthreads();
  }
}

// ---------------- binarize+pack x into padded bit image (halo = 0)
__global__ __launch_bounds__(256) void pack_x(const float* __restrict__ x,
                                              uint32_t* __restrict__ P)
{
  int g = blockIdx.x * 256 + threadIdx.x;   // 0 .. 32*PIMG-1 == 850175
  int n = g / PIMG;
  int r = g - n * PIMG;
  int pr = r / PRS;
  int pc = r - pr * PRS;
  uint32_t bits = 0;
  int h = pr - 1, w = pc - 1;
  if (h >= 0 && h < HH && w >= 0 && w < WW) {
    const float* xp = x + (size_t)n * CH * HWL + h * WW + w;
    #pragma unroll 8
    for (int c = 0; c < 32; ++c)
      bits |= (xp[(size_t)c * HWL] > 0.0f) ? (1u << c) : 0u;
  }
  P[g] = bits;
}

// ---------------- binary conv via xor+popcount; each thread does 4 pixels x 32 co
__global__ __launch_bounds__(256) void conv_pop(const uint32_t* __restrict__ P,
    const uint32_t* __restrict__ WP, const int* __restrict__ CORR,
    short* __restrict__ Y)
{
  __shared__ uint32_t wsh[288];
  __shared__ int csh[288];
  const int tid = threadIdx.x;
  for (int i = tid; i < 288; i += 256) { wsh[i] = WP[i]; csh[i] = CORR[i]; }
  __syncthreads();

  int g = blockIdx.x * 256 + tid;           // over 32*160*40 = 204800
  int w4 = g % 40;
  int t1 = g / 40;
  int h = t1 % 160;
  int n = t1 / 160;

  const uint32_t* base = P + n * PIMG + h * PRS + w4 * 4;
  uint32_t r[3][6];
  #pragma unroll
  for (int dy = 0; dy < 3; ++dy) {
    uint4 a = *reinterpret_cast<const uint4*>(base + dy * PRS);
    uint2 b = *reinterpret_cast<const uint2*>(base + dy * PRS + 4);
    r[dy][0] = a.x; r[dy][1] = a.y; r[dy][2] = a.z; r[dy][3] = a.w;
    r[dy][4] = b.x; r[dy][5] = b.y;
  }

  int rowc = (h == 0) ? 0 : ((h == 159) ? 6 : 3);
  int cls0  = rowc + ((w4 == 0) ? 0 : 1);
  int cls12 = rowc + 1;
  int cls3  = rowc + ((w4 == 39) ? 2 : 1);

  short* yb = Y + (size_t)n * CH * HWL + h * WW + w4 * 4;

  for (int co = 0; co < 32; ++co) {
    uint32_t wv[9];
    #pragma unroll
    for (int t = 0; t < 9; ++t) wv[t] = wsh[co * 9 + t];
    int a0 = 0, a1 = 0, a2 = 0, a3 = 0;
    #pragma unroll
    for (int dy = 0; dy < 3; ++dy) {
      #pragma unroll
      for (int dx = 0; dx < 3; ++dx) {
        uint32_t wvv = wv[dy * 3 + dx];
        a0 += __popc(r[dy][0 + dx] ^ wvv);
        a1 += __popc(r[dy][1 + dx] ^ wvv);
        a2 += __popc(r[dy][2 + dx] ^ wvv);
        a3 += __popc(r[dy][3 + dx] ^ wvv);
      }
    }
    int d0 = 288 - 2 * a0 - csh[cls0 * 32 + co];
    int d1 = 288 - 2 * a1 - csh[cls12 * 32 + co];
    int d2 = 288 - 2 * a2 - csh[cls12 * 32 + co];
    int d3 = 288 - 2 * a3 - csh[cls3 * 32 + co];
    *reinterpret_cast<short4*>(yb + (size_t)co * HWL) =
        make_short4((short)d0, (short)d1, (short)d2, (short)d3);
  }
}

// ---------------- per-channel integer stats from int16 conv output
__device__ inline void acc16(int u, int& s1, int& s2)
{
  int lo = (int)(short)(u & 0xffff);
  int hi = (int)(short)(u >> 16);
  s1 += lo + hi;
  s2 += lo * lo + hi * hi;
}

__global__ __launch_bounds__(256) void stats_k(const short* __restrict__ Y,
    int* __restrict__ S1, unsigned long long* __restrict__ S2)
{
  int c = blockIdx.x & 31;
  int chunk = blockIdx.x >> 5;               // 50 chunks of 16384 elems per channel
  int tid = threadIdx.x;
  int s1 = 0, s2 = 0;
  int e0 = chunk * 16384 + tid * 8;
  for (int it = 0; it < 8; ++it) {
    int e = e0 + it * 2048;
    int n = e / HWL;
    int i = e - n * HWL;
    int4 v = *reinterpret_cast<const int4*>(Y + (size_t)(n * CH + c) * HWL + i);
    acc16(v.x, s1, s2); acc16(v.y, s1, s2); acc16(v.z, s1, s2); acc16(v.w, s1, s2);
  }
  for (int off = 32; off > 0; off >>= 1) {
    s1 += __shfl_down(s1, off);
    s2 += __shfl_down(s2, off);
  }
  __shared__ int rs1[4], rs2[4];
  int wid = tid >> 6;
  if ((tid & 63) == 0) { rs1[wid] = s1; rs2[wid] = s2; }
  __syncthreads();
  if (tid == 0) {
    int t1 = rs1[0] + rs1[1] + rs1[2] + rs1[3];
    long long t2 = (long long)rs2[0] + rs2[1] + rs2[2] + rs2[3];
    atomicAdd(&S1[c], t1);
    atomicAdd(&S2[c], (unsigned long long)t2);
  }
}

// ---------------- fold BN into per-channel affine: out = A*dot + B (+ residual)
__global__ void finalize_stats(const int* __restrict__ S1,
    const unsigned long long* __restrict__ S2, const float* __restrict__ SC,
    const float* __restrict__ gamma, const float* __restrict__ beta,
    float* __restrict__ A, float* __restrict__ B)
{
  int c = threadIdx.x;
  if (c >= 32) return;
  double Np = (double)NPIX;
  double sc = (double)SC[0];
  double m  = sc * (double)S1[c] / Np;
  double ms = sc * sc * (double)(long long)S2[c] / Np;
  double var = ms - m * m;
  float inv = (float)(1.0 / sqrt(var + 1e-5));
  float g = gamma[c];
  A[c] = g * inv * (float)sc;
  B[c] = beta[c] - g * inv * (float)m;
}

// ---------------- BN1 + residual + write inner (to d_out) + re-pack bits
__global__ __launch_bounds__(256) void bnres_pack(const short* __restrict__ Y,
    const float* __restrict__ x, const float* __restrict__ A,
    const float* __restrict__ B, float* __restrict__ out, uint32_t* __restrict__ P)
{
  __shared__ float Ash[32], Bsh[32];
  int tid = threadIdx.x;
  if (tid < 32) { Ash[tid] = A[tid]; Bsh[tid] = B[tid]; }
  __syncthreads();
  int g = blockIdx.x * 256 + tid;            // over NPIX
  int n = g / HWL;
  int i = g - n * HWL;
  size_t base = (size_t)n * CH * HWL + i;
  uint32_t bits = 0;
  #pragma unroll 8
  for (int c = 0; c < 32; ++c) {
    size_t idx = base + (size_t)c * HWL;
    float v = fmaf(Ash[c], (float)Y[idx], Bsh[c]) + x[idx];
    out[idx] = v;
    bits |= (v > 0.0f) ? (1u << c) : 0u;
  }
  int h = i / WW, w = i - (i / WW) * WW;
  P[n * PIMG + (h + 1) * PRS + (w + 1)] = bits;
}

// ---------------- BN2 + residual, in place on d_out
__global__ __launch_bounds__(256) void bnres_final(const short* __restrict__ Y,
    const float* __restrict__ A, const float* __restrict__ B,
    float* __restrict__ out)
{
  __shared__ float Ash[32], Bsh[32];
  int tid = threadIdx.x;
  if (tid < 32) { Ash[tid] = A[tid]; Bsh[tid] = B[tid]; }
  __syncthreads();
  int g = blockIdx.x * 256 + tid;
  int n = g / HWL;
  int i = g - n * HWL;
  size_t base = (size_t)n * CH * HWL + i;
  #pragma unroll 8
  for (int c = 0; c < 32; ++c) {
    size_t idx = base + (size_t)c * HWL;
    float v = fmaf(Ash[c], (float)Y[idx], Bsh[c]) + out[idx];
    out[idx] = v;
  }
}

extern "C" void kernel_launch(void* const* d_in, const int* in_sizes, int n_in,
                              void* d_out, int out_size, void* d_ws, size_t ws_size,
                              hipStream_t stream)
{
  (void)in_sizes; (void)n_in; (void)out_size; (void)ws_size;
  const float* x  = (const float*)d_in[0];
  const float* w1 = (const float*)d_in[1];
  const float* g1 = (const float*)d_in[2];
  const float* b1 = (const float*)d_in[3];
  const float* w2 = (const float*)d_in[4];
  const float* g2 = (const float*)d_in[5];
  const float* b2 = (const float*)d_in[6];
  float* out = (float*)d_out;
  char* ws = (char*)d_ws;

  uint32_t* P    = (uint32_t*)(ws + OFF_P);
  short*    Y    = (short*)(ws + OFF_Y);
  uint32_t* WP   = (uint32_t*)(ws + OFF_WP);
  int*      CORR = (int*)(ws + OFF_CORR);
  float*    SC   = (float*)(ws + OFF_SC);
  int*      S1   = (int*)(ws + OFF_S1);
  unsigned long long* S2 = (unsigned long long*)(ws + OFF_S2);
  float*    AB   = (float*)(ws + OFF_AB);   // A1 B1 A2 B2, 32 floats each

  prep_k<<<1, 256, 0, stream>>>(w1, w2, WP, CORR, SC, S1, S2);
  pack_x<<<(NIMG * PIMG) / 256, 256, 0, stream>>>(x, P);

  conv_pop<<<(NIMG * HH * 40) / 256, 256, 0, stream>>>(P, WP, CORR, Y);
  stats_k<<<1600, 256, 0, stream>>>(Y, S1, S2);
  finalize_stats<<<1, 64, 0, stream>>>(S1, S2, SC, g1, b1, AB, AB + 32);
  bnres_pack<<<NPIX / 256, 256, 0, stream>>>(Y, x, AB, AB + 32, out, P);

  conv_pop<<<(NIMG * HH * 40) / 256, 256, 0, stream>>>(P, WP + 288, CORR + 288, Y);
  stats_k<<<1600, 256, 0, stream>>>(Y, S1 + 32, S2 + 32);
  finalize_stats<<<1, 64, 0, stream>>>(S1 + 32, S2 + 32, SC + 1, g2, b2, AB + 64, AB + 96);
  bnres_final<<<NPIX / 256, 256, 0, stream>>>(Y, AB + 64, AB + 96, out);
}